// Round 2
// baseline (1282.078 us; speedup 1.0000x reference)
//
#include <hip/hip_runtime.h>
#include <hip/hip_bf16.h>

// transformAttention fused kernel (round 2: f32 output fix)
// B=16, P=Q=12, N=2048, D=64, h=8 heads of head_dim 8, scale=1/sqrt(8).
// One wave handles one n-position end-to-end:
//   q/k/v projections (W_ff cols in VGPRs, STE rows broadcast-loaded from global)
//   -> QK^T via 8-lane shfl_xor butterfly -> in-register softmax -> PV
//   -> 2-layer FFN through a wave-private LDS row buffer -> f32 store.
// Round-1 bug: stored bf16 into what is actually a float32 output buffer
// (reference returns jnp.float32). Stub-vs-kernel absmax comparison proved it.

constexpr int Bb = 16;
constexpr int Pp = 12;
constexpr int Qq = 12;
constexpr int Nn = 2048;
constexpr int Dd = 64;
constexpr float SCALE = 0.35355339059327373f; // 1/sqrt(h=8)
constexpr int WAVES = 4;   // 256 threads
constexpr int NPW   = 2;   // n per wave

__global__ __launch_bounds__(256, 2)
void ta_fused(const float* __restrict__ x,
              const float* __restrict__ steP,
              const float* __restrict__ steQ,
              const float* __restrict__ Wff, const float* __restrict__ bff,
              const float* __restrict__ W1,  const float* __restrict__ b1,
              const float* __restrict__ W2,  const float* __restrict__ b2,
              float* __restrict__ out)
{
    __shared__ float sW[3][Dd * Dd];   // Wff, W1, W2 (48 KB)
    __shared__ float sB[3][Dd];
    __shared__ float sO[WAVES][Qq * Dd]; // per-wave out/hid buffer (12 KB)

    const int tid = threadIdx.x;

    // cooperative weight staging (float4)
    {
        const float4* src0 = (const float4*)Wff;
        const float4* src1 = (const float4*)W1;
        const float4* src2 = (const float4*)W2;
        float4* d0 = (float4*)sW[0];
        float4* d1 = (float4*)sW[1];
        float4* d2 = (float4*)sW[2];
        for (int i = tid; i < Dd * Dd / 4; i += 256) {
            d0[i] = src0[i];
            d1[i] = src1[i];
            d2[i] = src2[i];
        }
        if (tid < Dd) {
            sB[0][tid] = bff[tid];
            sB[1][tid] = b1[tid];
            sB[2][tid] = b2[tid];
        }
    }
    __syncthreads();

    const int wave = tid >> 6;
    const int lane = tid & 63;
    const int b = blockIdx.y;
    const int n0 = blockIdx.x * (WAVES * NPW) + wave * NPW;

    const float bf  = sB[0][lane];
    const float bi1 = sB[1][lane];
    const float bi2 = sB[2][lane];

    float wreg[Dd];

    for (int it = 0; it < NPW; ++it) {
        const int n = n0 + it;

        // ---- projections: lane holds column d=lane of W_ff ----
        #pragma unroll
        for (int e = 0; e < Dd; ++e) wreg[e] = sW[0][e * Dd + lane];

        float qv[Qq], kv[Pp], vv[Pp];

        #pragma unroll
        for (int r = 0; r < Qq; ++r) {
            const float4* row = (const float4*)(steQ + ((size_t)(b * Qq + r) * Nn + n) * Dd);
            float acc = bf;
            #pragma unroll
            for (int e4 = 0; e4 < Dd / 4; ++e4) {
                float4 s = row[e4];
                acc = fmaf(s.x, wreg[4 * e4 + 0], acc);
                acc = fmaf(s.y, wreg[4 * e4 + 1], acc);
                acc = fmaf(s.z, wreg[4 * e4 + 2], acc);
                acc = fmaf(s.w, wreg[4 * e4 + 3], acc);
            }
            qv[r] = acc;
        }
        #pragma unroll
        for (int r = 0; r < Pp; ++r) {
            const float4* row = (const float4*)(steP + ((size_t)(b * Pp + r) * Nn + n) * Dd);
            float acc = bf;
            #pragma unroll
            for (int e4 = 0; e4 < Dd / 4; ++e4) {
                float4 s = row[e4];
                acc = fmaf(s.x, wreg[4 * e4 + 0], acc);
                acc = fmaf(s.y, wreg[4 * e4 + 1], acc);
                acc = fmaf(s.z, wreg[4 * e4 + 2], acc);
                acc = fmaf(s.w, wreg[4 * e4 + 3], acc);
            }
            kv[r] = acc;
        }
        #pragma unroll
        for (int r = 0; r < Pp; ++r) {
            const float4* row = (const float4*)(x + ((size_t)(b * Pp + r) * Nn + n) * Dd);
            float acc = bf;
            #pragma unroll
            for (int e4 = 0; e4 < Dd / 4; ++e4) {
                float4 s = row[e4];
                acc = fmaf(s.x, wreg[4 * e4 + 0], acc);
                acc = fmaf(s.y, wreg[4 * e4 + 1], acc);
                acc = fmaf(s.z, wreg[4 * e4 + 2], acc);
                acc = fmaf(s.w, wreg[4 * e4 + 3], acc);
            }
            vv[r] = acc;
        }

        // ---- attention: lane = h*8 + kk; butterfly sums over kk (8 lanes) ----
        #pragma unroll
        for (int r = 0; r < Qq; ++r) {
            float t[Pp];
            #pragma unroll
            for (int p = 0; p < Pp; ++p) t[p] = qv[r] * kv[p];
            #pragma unroll
            for (int p = 0; p < Pp; ++p) {
                t[p] += __shfl_xor(t[p], 1);
                t[p] += __shfl_xor(t[p], 2);
                t[p] += __shfl_xor(t[p], 4);
            }
            // now every lane of the 8-lane group holds scores[h][r][p] (unscaled)
            float mx = t[0];
            #pragma unroll
            for (int p = 1; p < Pp; ++p) mx = fmaxf(mx, t[p]);
            float sum = 0.f;
            #pragma unroll
            for (int p = 0; p < Pp; ++p) {
                t[p] = __expf((t[p] - mx) * SCALE);
                sum += t[p];
            }
            float o = 0.f;
            #pragma unroll
            for (int p = 0; p < Pp; ++p) o = fmaf(t[p], vv[p], o);
            sO[wave][r * Dd + lane] = o / sum;
        }

        // ---- FFN layer 1 (relu) ----
        #pragma unroll
        for (int e = 0; e < Dd; ++e) wreg[e] = sW[1][e * Dd + lane];
        #pragma unroll
        for (int r = 0; r < Qq; ++r) {
            const float4* row = (const float4*)&sO[wave][r * Dd];
            float acc = bi1;
            #pragma unroll
            for (int e4 = 0; e4 < Dd / 4; ++e4) {
                float4 s = row[e4];
                acc = fmaf(s.x, wreg[4 * e4 + 0], acc);
                acc = fmaf(s.y, wreg[4 * e4 + 1], acc);
                acc = fmaf(s.z, wreg[4 * e4 + 2], acc);
                acc = fmaf(s.w, wreg[4 * e4 + 3], acc);
            }
            // safe overwrite: row r fully consumed (acc depends on all reads)
            sO[wave][r * Dd + lane] = fmaxf(acc, 0.f);
        }

        // ---- FFN layer 2 + f32 store ----
        #pragma unroll
        for (int e = 0; e < Dd; ++e) wreg[e] = sW[2][e * Dd + lane];
        #pragma unroll
        for (int r = 0; r < Qq; ++r) {
            const float4* row = (const float4*)&sO[wave][r * Dd];
            float acc = bi2;
            #pragma unroll
            for (int e4 = 0; e4 < Dd / 4; ++e4) {
                float4 s = row[e4];
                acc = fmaf(s.x, wreg[4 * e4 + 0], acc);
                acc = fmaf(s.y, wreg[4 * e4 + 1], acc);
                acc = fmaf(s.z, wreg[4 * e4 + 2], acc);
                acc = fmaf(s.w, wreg[4 * e4 + 3], acc);
            }
            out[((size_t)(b * Qq + r) * Nn + n) * Dd + lane] = acc;
        }
    }
}

extern "C" void kernel_launch(void* const* d_in, const int* in_sizes, int n_in,
                              void* d_out, int out_size, void* d_ws, size_t ws_size,
                              hipStream_t stream) {
    const float* x    = (const float*)d_in[0];
    const float* steP = (const float*)d_in[1];
    const float* steQ = (const float*)d_in[2];
    const float* Wff  = (const float*)d_in[3];
    const float* bff  = (const float*)d_in[4];
    const float* W1   = (const float*)d_in[5];
    const float* b1   = (const float*)d_in[6];
    const float* W2   = (const float*)d_in[7];
    const float* b2   = (const float*)d_in[8];
    float* out = (float*)d_out;

    dim3 grid(Nn / (WAVES * NPW), Bb);
    ta_fused<<<grid, 256, 0, stream>>>(x, steP, steQ, Wff, bff, W1, b1, W2, b2, out);
}

// Round 3
// 205.604 us; speedup vs baseline: 6.2357x; 6.2357x over previous
//
#include <hip/hip_runtime.h>
#include <hip/hip_bf16.h>

// transformAttention fused MFMA kernel (round 3)
// B=16, S=P=Q=12, N=2048, D=64, h=8 heads of dim 8.
// Block = (b, 16-n tile), 512 threads = 8 waves:
//   phase 1: q/k/v projections via mfma_f32_16x16x32_bf16 (M-tile = 16 n for fixed s,
//            A-frags straight from global f32 -> cvt bf16; W_ff frags in VGPRs),
//            C (+bias) -> LDS bf16 [t][s][n][d], XOR-swizzled (n&12)<<3.
//   phase 2: attention per n, lane = d (round-2-verified butterfly over 8-lane head
//            groups), attnOut kept in registers (12 s x 2 n per wave).
//   phase 3: FFN via MFMA with M-tile = 16 rows mixing (s,n) per wave; wave-private
//            [16][69]-padded f32 LDS buffers overlaid on the dead qkv region.
// Output stored f32 (round-2-verified convention).

typedef __attribute__((ext_vector_type(8))) short bf16x8;
typedef __attribute__((ext_vector_type(4))) float f32x4;

constexpr int Bb = 16, Ss = 12, Nn = 2048, Dd = 64;
constexpr float SCALE = 0.35355339059327373f; // 1/sqrt(8)

#define MFMA16(A, B, C) __builtin_amdgcn_mfma_f32_16x16x32_bf16((A), (B), (C), 0, 0, 0)

__device__ __forceinline__ short f2bf(float f) {
    __hip_bfloat16 h = __float2bfloat16(f);
    short s;
    __builtin_memcpy(&s, &h, 2);
    return s;
}
__device__ __forceinline__ float bf2f(short v) {
    unsigned u = ((unsigned)(unsigned short)v) << 16;
    float f;
    __builtin_memcpy(&f, &u, 4);
    return f;
}
__device__ __forceinline__ void lds_fence() {
    asm volatile("s_waitcnt lgkmcnt(0)" ::: "memory");
    __builtin_amdgcn_sched_barrier(0);
}

// qkv LDS: [t][s][n(16)][d(64)] bf16, byte = t*24576 + s*2048 + n*128 + (2d ^ ((n&12)<<3))
// FFN buf: per wave 2 tiles of [16 rows][69 f32] at smem + w*8832 + tile*4416

__global__ __launch_bounds__(512, 4)
void ta_mfma(const float* __restrict__ x,
             const float* __restrict__ steP,
             const float* __restrict__ steQ,
             const float* __restrict__ Wff, const float* __restrict__ bff,
             const float* __restrict__ W1,  const float* __restrict__ b1,
             const float* __restrict__ W2,  const float* __restrict__ b2,
             float* __restrict__ out)
{
    alignas(16) __shared__ char smem[73728];

    const int tid = threadIdx.x;
    const int w   = tid >> 6;
    const int l   = tid & 63;
    const int l15 = l & 15;
    const int l4  = l >> 4;
    const int b   = blockIdx.y;
    const int n0  = blockIdx.x * 16;

    // ---- W_ff B-frags: lane l holds W[kc*32 + l4*8 + j][nt*16 + l15] ----
    bf16x8 wf[4][2];
    #pragma unroll
    for (int nt = 0; nt < 4; ++nt)
        #pragma unroll
        for (int kc = 0; kc < 2; ++kc)
            #pragma unroll
            for (int j = 0; j < 8; ++j)
                wf[nt][kc][j] = f2bf(Wff[(kc * 32 + l4 * 8 + j) * 64 + nt * 16 + l15]);
    float bfv[4];
    #pragma unroll
    for (int nt = 0; nt < 4; ++nt) bfv[nt] = bff[nt * 16 + l15];

    // ---- phase 1: projections (36 jobs = 3 tensors x 12 s, round-robin over waves) ----
    for (int j = w; j < 36; j += 8) {
        const int t = j / 12, s = j % 12;
        const float* base = (t == 0) ? steQ : (t == 1) ? steP : x;
        base += ((size_t)(b * Ss + s) * Nn + n0 + l15) * Dd + l4 * 8;

        bf16x8 a[2];
        #pragma unroll
        for (int kc = 0; kc < 2; ++kc) {
            float4 p0 = *(const float4*)(base + kc * 32);
            float4 p1 = *(const float4*)(base + kc * 32 + 4);
            a[kc][0] = f2bf(p0.x); a[kc][1] = f2bf(p0.y);
            a[kc][2] = f2bf(p0.z); a[kc][3] = f2bf(p0.w);
            a[kc][4] = f2bf(p1.x); a[kc][5] = f2bf(p1.y);
            a[kc][6] = f2bf(p1.z); a[kc][7] = f2bf(p1.w);
        }
        #pragma unroll
        for (int nt = 0; nt < 4; ++nt) {
            f32x4 acc = { bfv[nt], bfv[nt], bfv[nt], bfv[nt] };
            acc = MFMA16(a[0], wf[nt][0], acc);
            acc = MFMA16(a[1], wf[nt][1], acc);
            #pragma unroll
            for (int q = 0; q < 4; ++q) {
                const int n = l4 * 4 + q;
                const int d = nt * 16 + l15;
                const int byte = t * 24576 + s * 2048 + n * 128 + ((2 * d) ^ ((n & 12) << 3));
                *(short*)(smem + byte) = f2bf(acc[q]);
            }
        }
    }
    __syncthreads();

    // ---- phase 2: attention, lane = d, 2 n per wave ----
    float attnOut[12][2];
    #pragma unroll
    for (int ni = 0; ni < 2; ++ni) {
        const int n = w * 2 + ni;
        const int dbyte = (2 * l) ^ ((n & 12) << 3);
        float qv[12], kv[12], vv[12];
        #pragma unroll
        for (int s = 0; s < 12; ++s) qv[s] = bf2f(*(short*)(smem +         s * 2048 + n * 128 + dbyte));
        #pragma unroll
        for (int s = 0; s < 12; ++s) kv[s] = bf2f(*(short*)(smem + 24576 + s * 2048 + n * 128 + dbyte));
        #pragma unroll
        for (int s = 0; s < 12; ++s) vv[s] = bf2f(*(short*)(smem + 49152 + s * 2048 + n * 128 + dbyte));

        #pragma unroll
        for (int r = 0; r < 12; ++r) {
            float tt[12];
            #pragma unroll
            for (int p = 0; p < 12; ++p) tt[p] = qv[r] * kv[p];
            #pragma unroll
            for (int p = 0; p < 12; ++p) {
                tt[p] += __shfl_xor(tt[p], 1);
                tt[p] += __shfl_xor(tt[p], 2);
                tt[p] += __shfl_xor(tt[p], 4);
            }
            float mx = tt[0];
            #pragma unroll
            for (int p = 1; p < 12; ++p) mx = fmaxf(mx, tt[p]);
            float sum = 0.f;
            #pragma unroll
            for (int p = 0; p < 12; ++p) { tt[p] = __expf((tt[p] - mx) * SCALE); sum += tt[p]; }
            float o = 0.f;
            #pragma unroll
            for (int p = 0; p < 12; ++p) o = fmaf(tt[p], vv[p], o);
            attnOut[r][ni] = o / sum;
        }
    }
    __syncthreads();   // all waves done reading qkv; region is reusable

    // ---- phase 3: FFN (wave-private tiles: rows r = sidx*2 + nidx; tile0 s=0..7, tile1 s=8..11) ----
    float* buf0 = (float*)(smem + w * 8832);
    float* buf1 = (float*)(smem + w * 8832 + 4416);

    // write attnOut tiles (lane = d)
    #pragma unroll
    for (int s = 0; s < 8; ++s)
        #pragma unroll
        for (int ni = 0; ni < 2; ++ni)
            buf0[(s * 2 + ni) * 69 + l] = attnOut[s][ni];
    #pragma unroll
    for (int s = 0; s < 4; ++s)
        #pragma unroll
        for (int ni = 0; ni < 2; ++ni)
            buf1[(s * 2 + ni) * 69 + l] = attnOut[8 + s][ni];
    #pragma unroll
    for (int r = 8; r < 16; ++r) buf1[r * 69 + l] = 0.f;   // dead rows: keep finite
    lds_fence();

    // W1 frags + biases
    bf16x8 w1f[4][2];
    #pragma unroll
    for (int nt = 0; nt < 4; ++nt)
        #pragma unroll
        for (int kc = 0; kc < 2; ++kc)
            #pragma unroll
            for (int j = 0; j < 8; ++j)
                w1f[nt][kc][j] = f2bf(W1[(kc * 32 + l4 * 8 + j) * 64 + nt * 16 + l15]);
    float b1v[4];
    #pragma unroll
    for (int nt = 0; nt < 4; ++nt) b1v[nt] = b1[nt * 16 + l15];

    // FFN1 for both tiles: hid = relu(attn @ W1 + b1), written back in place
    #pragma unroll
    for (int tile = 0; tile < 2; ++tile) {
        float* buf = tile ? buf1 : buf0;
        bf16x8 a[2];
        #pragma unroll
        for (int kc = 0; kc < 2; ++kc)
            #pragma unroll
            for (int j = 0; j < 8; ++j)
                a[kc][j] = f2bf(buf[l15 * 69 + kc * 32 + l4 * 8 + j]);
        f32x4 h[4];
        #pragma unroll
        for (int nt = 0; nt < 4; ++nt) {
            f32x4 acc = { b1v[nt], b1v[nt], b1v[nt], b1v[nt] };
            acc = MFMA16(a[0], w1f[nt][0], acc);
            acc = MFMA16(a[1], w1f[nt][1], acc);
            #pragma unroll
            for (int q = 0; q < 4; ++q) h[nt][q] = fmaxf(acc[q], 0.f);
        }
        #pragma unroll
        for (int nt = 0; nt < 4; ++nt)
            #pragma unroll
            for (int q = 0; q < 4; ++q)
                buf[(l4 * 4 + q) * 69 + nt * 16 + l15] = h[nt][q];
    }
    lds_fence();

    // W2 frags + biases (w1f dead -> register reuse)
    bf16x8 w2f[4][2];
    #pragma unroll
    for (int nt = 0; nt < 4; ++nt)
        #pragma unroll
        for (int kc = 0; kc < 2; ++kc)
            #pragma unroll
            for (int j = 0; j < 8; ++j)
                w2f[nt][kc][j] = f2bf(W2[(kc * 32 + l4 * 8 + j) * 64 + nt * 16 + l15]);
    float b2v[4];
    #pragma unroll
    for (int nt = 0; nt < 4; ++nt) b2v[nt] = b2[nt * 16 + l15];

    // FFN2 for both tiles: out = hid @ W2 + b2 -> global f32
    #pragma unroll
    for (int tile = 0; tile < 2; ++tile) {
        float* buf = tile ? buf1 : buf0;
        bf16x8 a[2];
        #pragma unroll
        for (int kc = 0; kc < 2; ++kc)
            #pragma unroll
            for (int j = 0; j < 8; ++j)
                a[kc][j] = f2bf(buf[l15 * 69 + kc * 32 + l4 * 8 + j]);
        #pragma unroll
        for (int nt = 0; nt < 4; ++nt) {
            f32x4 acc = { b2v[nt], b2v[nt], b2v[nt], b2v[nt] };
            acc = MFMA16(a[0], w2f[nt][0], acc);
            acc = MFMA16(a[1], w2f[nt][1], acc);
            #pragma unroll
            for (int q = 0; q < 4; ++q) {
                const int row  = l4 * 4 + q;
                const int sidx = row >> 1, ni = row & 1;
                const int s    = tile * 8 + sidx;
                if (s < 12) {
                    const int n = n0 + w * 2 + ni;
                    out[((size_t)(b * Ss + s) * Nn + n) * Dd + nt * 16 + l15] = acc[q];
                }
            }
        }
    }
}

extern "C" void kernel_launch(void* const* d_in, const int* in_sizes, int n_in,
                              void* d_out, int out_size, void* d_ws, size_t ws_size,
                              hipStream_t stream) {
    const float* x    = (const float*)d_in[0];
    const float* steP = (const float*)d_in[1];
    const float* steQ = (const float*)d_in[2];
    const float* Wff  = (const float*)d_in[3];
    const float* bff  = (const float*)d_in[4];
    const float* W1   = (const float*)d_in[5];
    const float* b1   = (const float*)d_in[6];
    const float* W2   = (const float*)d_in[7];
    const float* b2   = (const float*)d_in[8];
    float* out = (float*)d_out;

    dim3 grid(Nn / 16, Bb);
    ta_mfma<<<grid, 512, 0, stream>>>(x, steP, steQ, Wff, bff, W1, b1, W2, b2, out);
}